// Round 4
// baseline (437.748 us; speedup 1.0000x reference)
//
#include <hip/hip_runtime.h>

// Haar DWT LEVEL=1 on x:(32, 4096, 512) fp32.
// out[:, 0:2048, :]    = (x[:, 0::2, :] + x[:, 1::2, :]) * 1/sqrt(2)
// out[:, 2048:4096, :] = (x[:, 0::2, :] - x[:, 1::2, :]) * 1/sqrt(2)
//
// Pure streaming: 256 MiB in + 256 MiB out, zero reuse. Floor ~85 us @ 6.3 TB/s.
// Grid-stride persistent form: 4096 blocks x 256 thr, 8 vec4 units/thread ->
// compiler can pipeline 16 loads in flight (ILP), amortizes wg dispatch.
// Non-temporal ops keep the streams out of L2's LRU.

#define B_    32
#define L_    4096
#define HALF_ 2048
#define F4_   128                  // 512 floats / 4 per vec4
#define NUNITS (B_ * HALF_ * F4_) // 8,388,608 vec4 work units
#define NBLK  4096
#define NTHR  256
#define PERTHR (NUNITS / (NBLK * NTHR))  // 8

typedef float v4 __attribute__((ext_vector_type(4)));

__global__ __launch_bounds__(NTHR) void haar_dwt1(const v4* __restrict__ x,
                                                  v4* __restrict__ out) {
    const float inv_sqrt2 = 0.70710678118654752440f;
    unsigned tid0 = blockIdx.x * NTHR + threadIdx.x;
    const unsigned stride = NBLK * NTHR;           // 1,048,576

#pragma unroll
    for (int u = 0; u < PERTHR; ++u) {
        unsigned tid = tid0 + u * stride;
        unsigned f4 = tid & (F4_ - 1);             // vec4 index within 512-float row
        unsigned p  = tid >> 7;                    // pair index: b*2048 + i
        unsigned i  = p & (HALF_ - 1);
        unsigned b  = p >> 11;

        unsigned in_off = (b * L_ + 2u * i) * F4_ + f4;
        v4 x0 = __builtin_nontemporal_load(x + in_off);
        v4 x1 = __builtin_nontemporal_load(x + in_off + F4_);

        v4 cA = (x0 + x1) * inv_sqrt2;
        v4 cD = (x0 - x1) * inv_sqrt2;

        __builtin_nontemporal_store(cA, out + (b * L_ + i) * F4_ + f4);
        __builtin_nontemporal_store(cD, out + (b * L_ + HALF_ + i) * F4_ + f4);
    }
}

extern "C" void kernel_launch(void* const* d_in, const int* in_sizes, int n_in,
                              void* d_out, int out_size, void* d_ws, size_t ws_size,
                              hipStream_t stream) {
    const v4* x = (const v4*)d_in[0];
    v4* out = (v4*)d_out;
    haar_dwt1<<<NBLK, NTHR, 0, stream>>>(x, out);
}

// Round 5
// 412.478 us; speedup vs baseline: 1.0613x; 1.0613x over previous
//
#include <hip/hip_runtime.h>

// Haar DWT LEVEL=1 on x:(32, 4096, 512) fp32.
// out[:, 0:2048, :]    = (x[:, 0::2, :] + x[:, 1::2, :]) * 1/sqrt(2)
// out[:, 2048:4096, :] = (x[:, 0::2, :] - x[:, 1::2, :]) * 1/sqrt(2)
//
// Pure streaming: 256 MiB in + 256 MiB out, zero reuse; min traffic achieved,
// fully coalesced 16 B/lane. Non-temporal keeps streams out of L2's LRU.
// R4 lesson: flat one-thread-per-vec4 beats grid-stride persistent here
// (sequential per-wave address walk = best DRAM locality).

#define B_    32
#define L_    4096
#define HALF_ 2048
#define F4_   128   // 512 floats / 4 per vec4

typedef float v4 __attribute__((ext_vector_type(4)));

__global__ __launch_bounds__(256) void haar_dwt1(const v4* __restrict__ x,
                                                 v4* __restrict__ out) {
    const float inv_sqrt2 = 0.70710678118654752440f;
    unsigned tid = blockIdx.x * 256u + threadIdx.x;   // [0, 32*2048*128)
    unsigned f4 = tid & (F4_ - 1);                    // vec4 index within 512-float row
    unsigned p  = tid >> 7;                           // pair index: b*2048 + i
    unsigned i  = p & (HALF_ - 1);
    unsigned b  = p >> 11;

    unsigned in_off = (b * L_ + 2u * i) * F4_ + f4;
    v4 x0 = __builtin_nontemporal_load(x + in_off);
    v4 x1 = __builtin_nontemporal_load(x + in_off + F4_);

    v4 cA = (x0 + x1) * inv_sqrt2;
    v4 cD = (x0 - x1) * inv_sqrt2;

    __builtin_nontemporal_store(cA, out + (b * L_ + i) * F4_ + f4);
    __builtin_nontemporal_store(cD, out + (b * L_ + HALF_ + i) * F4_ + f4);
}

extern "C" void kernel_launch(void* const* d_in, const int* in_sizes, int n_in,
                              void* d_out, int out_size, void* d_ws, size_t ws_size,
                              hipStream_t stream) {
    const v4* x = (const v4*)d_in[0];
    v4* out = (v4*)d_out;
    // total vec4 units = 32*2048*128 = 8,388,608 -> 32768 blocks of 256
    int n4 = B_ * HALF_ * F4_;
    haar_dwt1<<<n4 / 256, 256, 0, stream>>>(x, out);
}